// Round 5
// baseline (240.942 us; speedup 1.0000x reference)
//
#include <hip/hip_runtime.h>

#define NN 10000
#define KK 64
#define CC 128
#define OUTOFF (NN * CC)
#define ROWS 20            // rows per kA block
#define NCH 500            // kA blocks: 500*20 == 10000
#define PART_F4 4096       // float4 per partial tile [2][64][32]

// ws float offsets
#define ROW_OFF  ((size_t)NCH * 16384)      // partials end: 8.192M floats (32 MB)
#define UVW_OFF  (ROW_OFF + 16384)

__device__ __forceinline__ float4 f4fma(float s, float4 v, float4 a) {
    a.x = fmaf(s, v.x, a.x); a.y = fmaf(s, v.y, a.y);
    a.z = fmaf(s, v.z, a.z); a.w = fmaf(s, v.w, a.w);
    return a;
}
__device__ __forceinline__ float4 f4add(float4 a, float4 b) {
    a.x += b.x; a.y += b.y; a.z += b.z; a.w += b.w; return a;
}

// ---------------- kA: 20-row chunk -> partial U,V  (rep-looped, idempotent) ----------------
__global__ __launch_bounds__(256) void kA(const float* __restrict__ re,
                                          const float* __restrict__ im,
                                          const float* __restrict__ Qr,
                                          const float* __restrict__ Qi,
                                          float* __restrict__ part, int reps)
{
    __shared__ float4 smem[1920];   // Qr[20][16] | Qi[20][16] | re[20][32] | im[20][32]
    const int t = threadIdx.x;
    const int bid = blockIdx.x;
    for (int rep = 0; rep < reps; ++rep) {
        asm volatile("" ::: "memory");   // block cross-rep hoisting: recompute for real
        {
            const float4* gqr = (const float4*)Qr;
            const float4* gqi = (const float4*)Qi;
            const float4* gre = (const float4*)re;
            const float4* gim = (const float4*)im;
            for (int i = t; i < 1920; i += 256) {
                float4 v;
                if (i < 320)       v = gqr[(size_t)bid * 320 + i];
                else if (i < 640)  v = gqi[(size_t)bid * 320 + (i - 320)];
                else if (i < 1280) v = gre[(size_t)bid * 640 + (i - 640)];
                else               v = gim[(size_t)bid * 640 + (i - 1280)];
                smem[i] = v;
            }
        }
        __syncthreads();
        const int kt = t >> 4;       // k-quad 0..15
        const int c8 = t & 15;       // 8-col group 0..15
        float aU[4][8] = {}, aV[4][8] = {};
#pragma unroll 4
        for (int rr = 0; rr < ROWS; ++rr) {
            float4 q_r = smem[rr * 16 + kt];
            float4 q_i = smem[320 + rr * 16 + kt];
            float4 x_r0 = smem[640 + rr * 32 + c8 * 2];
            float4 x_r1 = smem[640 + rr * 32 + c8 * 2 + 1];
            float4 x_i0 = smem[1280 + rr * 32 + c8 * 2];
            float4 x_i1 = smem[1280 + rr * 32 + c8 * 2 + 1];
            float qr_[4] = {q_r.x, q_r.y, q_r.z, q_r.w};
            float qi_[4] = {q_i.x, q_i.y, q_i.z, q_i.w};
            float xr_[8] = {x_r0.x, x_r0.y, x_r0.z, x_r0.w, x_r1.x, x_r1.y, x_r1.z, x_r1.w};
            float xi_[8] = {x_i0.x, x_i0.y, x_i0.z, x_i0.w, x_i1.x, x_i1.y, x_i1.z, x_i1.w};
#pragma unroll
            for (int a = 0; a < 4; ++a)
#pragma unroll
                for (int b = 0; b < 8; ++b) {
                    aU[a][b] = fmaf(qr_[a], xr_[b], aU[a][b]);
                    aU[a][b] = fmaf(qi_[a], xi_[b], aU[a][b]);
                    aV[a][b] = fmaf(qi_[a], xr_[b], aV[a][b]);
                    aV[a][b] = fmaf(-qr_[a], xi_[b], aV[a][b]);
                }
        }
        float* base = part + (size_t)bid * 16384;
        const int k0 = kt * 4, c0 = c8 * 8;
#pragma unroll
        for (int a = 0; a < 4; ++a) {
            *(float4*)(base + (k0 + a) * CC + c0)            = make_float4(aU[a][0], aU[a][1], aU[a][2], aU[a][3]);
            *(float4*)(base + (k0 + a) * CC + c0 + 4)        = make_float4(aU[a][4], aU[a][5], aU[a][6], aU[a][7]);
            *(float4*)(base + 8192 + (k0 + a) * CC + c0)     = make_float4(aV[a][0], aV[a][1], aV[a][2], aV[a][3]);
            *(float4*)(base + 8192 + (k0 + a) * CC + c0 + 4) = make_float4(aV[a][4], aV[a][5], aV[a][6], aV[a][7]);
        }
        __syncthreads();   // protect smem before next rep's overwrite
    }
}

// ---------------- kR1: reduce 500 partials -> row (rep-looped) ----------------
__global__ __launch_bounds__(512) void kR1(const float* __restrict__ part,
                                           float* __restrict__ row, int reps)
{
    __shared__ float4 red4[512];
    const int t = threadIdx.x;
    for (int rep = 0; rep < reps; ++rep) {
        asm volatile("" ::: "memory");
        const int i = t & 15;
        const int g = t >> 4;
        const int o = blockIdx.x * 16 + i;
        const float4* p = (const float4*)part + (size_t)g * PART_F4 + o;
        const float4 z = make_float4(0.f, 0.f, 0.f, 0.f);
        float4 s0 = z, s1 = z, s2 = z, s3 = z;
        int pp = g;
        for (; pp + 96 < NCH; pp += 128) {
            s0 = f4add(s0, p[0]);
            s1 = f4add(s1, p[(size_t)32 * PART_F4]);
            s2 = f4add(s2, p[(size_t)64 * PART_F4]);
            s3 = f4add(s3, p[(size_t)96 * PART_F4]);
            p += (size_t)128 * PART_F4;
        }
        for (; pp < NCH; pp += 32) {
            s0 = f4add(s0, p[0]);
            p += (size_t)32 * PART_F4;
        }
        red4[t] = f4add(f4add(s0, s1), f4add(s2, s3));
        __syncthreads();
        if (t < 16) {
            float4 tot = z;
#pragma unroll
            for (int gg = 0; gg < 32; ++gg) tot = f4add(tot, red4[gg * 16 + t]);
            ((float4*)row)[blockIdx.x * 16 + t] = tot;
        }
        __syncthreads();
    }
}

// ---------------- kR2: UVW = TT * (row @ W) (rep-looped) ----------------
__global__ __launch_bounds__(128) void kR2(const float* __restrict__ row,
                                           const float* __restrict__ Ritz,
                                           const int* __restrict__ ldp,
                                           const float* __restrict__ W,
                                           float* __restrict__ UVW, int reps)
{
    __shared__ float rowS[128];
    const int t = threadIdx.x;
    const int m = blockIdx.x >> 6, k = blockIdx.x & 63;
    for (int rep = 0; rep < reps; ++rep) {
        asm volatile("" ::: "memory");
        rowS[t] = row[m * 8192 + k * 128 + t];
        __syncthreads();
        float acc = 0.f;
#pragma unroll 8
        for (int cp = 0; cp < 128; ++cp)
            acc = fmaf(rowS[cp], W[cp * 128 + t], acc);
        const int ld = *ldp;
        const float rz = Ritz[k];
        float tt = 1.f;
        for (int i = 0; i < ld; ++i) tt *= rz;
        UVW[m * 8192 + k * 128 + t] = tt * acc;
        __syncthreads();
    }
}

// ---------------- kC: res = Q @ UVW + masked-ReLU (rep-looped) ----------------
__global__ __launch_bounds__(128) void kC(const float* __restrict__ re,
                                          const float* __restrict__ im,
                                          const float* __restrict__ Qr,
                                          const float* __restrict__ Qi,
                                          const float* __restrict__ UVW,
                                          float* __restrict__ out, int reps)
{
    const int t = threadIdx.x;
    const int ct = t & 31;
    const int rq = t >> 5;
    const int r0 = blockIdx.x * 16 + rq * 4;
    for (int rep = 0; rep < reps; ++rep) {
        asm volatile("" ::: "memory");
        const float4* U4 = (const float4*)UVW;
        const float4* V4 = U4 + 2048;
        const float4* qr0 = (const float4*)(Qr + (size_t)r0 * KK);
        const float4* qi0 = (const float4*)(Qi + (size_t)r0 * KK);
        const float4 z = make_float4(0.f, 0.f, 0.f, 0.f);
        float4 R[4] = {z, z, z, z}, I[4] = {z, z, z, z};
#pragma unroll 4
        for (int k4 = 0; k4 < 16; ++k4) {
            float4 qr[4], qi[4];
#pragma unroll
            for (int j = 0; j < 4; ++j) {
                qr[j] = qr0[j * 16 + k4];
                qi[j] = qi0[j * 16 + k4];
            }
#pragma unroll
            for (int jj = 0; jj < 4; ++jj) {
                const int k = k4 * 4 + jj;
                float4 uw = U4[k * 32 + ct];
                float4 vw = V4[k * 32 + ct];
#pragma unroll
                for (int j = 0; j < 4; ++j) {
                    float ar[4] = {qr[j].x, qr[j].y, qr[j].z, qr[j].w};
                    float ai[4] = {qi[j].x, qi[j].y, qi[j].z, qi[j].w};
                    R[j] = f4fma(ar[jj], uw, R[j]); R[j] = f4fma(ai[jj], vw, R[j]);
                    I[j] = f4fma(ai[jj], uw, I[j]); I[j] = f4fma(-ar[jj], vw, I[j]);
                }
            }
        }
        const int cc = ct * 4;
#pragma unroll
        for (int j = 0; j < 4; ++j) {
            const int row = r0 + j;
            float4 rin = *(const float4*)(re + (size_t)row * CC + cc);
            float4 iin = *(const float4*)(im + (size_t)row * CC + cc);
            float4 orr, oii;
            orr.x = rin.x + (R[j].x >= 0.f ? R[j].x : 0.f); oii.x = iin.x + (R[j].x >= 0.f ? I[j].x : 0.f);
            orr.y = rin.y + (R[j].y >= 0.f ? R[j].y : 0.f); oii.y = iin.y + (R[j].y >= 0.f ? I[j].y : 0.f);
            orr.z = rin.z + (R[j].z >= 0.f ? R[j].z : 0.f); oii.z = iin.z + (R[j].z >= 0.f ? I[j].z : 0.f);
            orr.w = rin.w + (R[j].w >= 0.f ? R[j].w : 0.f); oii.w = iin.w + (R[j].w >= 0.f ? I[j].w : 0.f);
            *(float4*)(out + (size_t)row * CC + cc)          = orr;
            *(float4*)(out + OUTOFF + (size_t)row * CC + cc) = oii;
        }
    }
}

extern "C" void kernel_launch(void* const* d_in, const int* in_sizes, int n_in,
                              void* d_out, int out_size, void* d_ws, size_t ws_size,
                              hipStream_t stream) {
    const float* re   = (const float*)d_in[0];
    const float* im   = (const float*)d_in[1];
    const float* Qr   = (const float*)d_in[2];
    const float* Qi   = (const float*)d_in[3];
    const float* Ritz = (const float*)d_in[4];
    const float* W    = (const float*)d_in[5];
    const int*   ldp  = (const int*)d_in[6];
    float* out = (float*)d_out;
    float* ws  = (float*)d_ws;

    float* part = ws;                      // 500 * 16384 floats (32 MB)
    float* row  = ws + ROW_OFF;            // 16384 floats
    float* UVW  = ws + UVW_OFF;            // 16384 floats

    // DIAGNOSTIC ROUND: idempotent repeat loops push each kernel above the
    // 44us poison-fills into rocprof's top-5 so we finally get per-kernel
    // counters. dur_us is intentionally sacrificed this round.
    kA <<<NCH, 256, 0, stream>>>(re, im, Qr, Qi, part, 4);
    kR1<<<256, 512, 0, stream>>>(part, row, 4);
    kR2<<<128, 128, 0, stream>>>(row, Ritz, ldp, W, UVW, 8);
    kC <<<625, 128, 0, stream>>>(re, im, Qr, Qi, UVW, out, 4);
}

// Round 6
// 122.149 us; speedup vs baseline: 1.9725x; 1.9725x over previous
//
#include <hip/hip_runtime.h>

#define NN 10000
#define KK 64
#define CC 128
#define OUTOFF (NN * CC)
#define ROWS 16            // rows per kA block
#define NCH 625            // kA blocks: 625*16 == 10000
#define PART_F4 4096       // float4 per partial tile [2][64][32]

// ws float offsets
#define UVW_OFF  ((size_t)NCH * 16384)      // partials end: 10.24M floats (41 MB)

__device__ __forceinline__ float4 f4fma(float s, float4 v, float4 a) {
    a.x = fmaf(s, v.x, a.x); a.y = fmaf(s, v.y, a.y);
    a.z = fmaf(s, v.z, a.z); a.w = fmaf(s, v.w, a.w);
    return a;
}
__device__ __forceinline__ float4 f4add(float4 a, float4 b) {
    a.x += b.x; a.y += b.y; a.z += b.z; a.w += b.w; return a;
}

// ---------------- kA: 16-row chunk -> partial U,V ----------------
// 625 blocks x 256 threads; thread = 4k x 8c register tile (64 accumulators)
__global__ __launch_bounds__(256) void kA(const float* __restrict__ re,
                                          const float* __restrict__ im,
                                          const float* __restrict__ Qr,
                                          const float* __restrict__ Qi,
                                          float* __restrict__ part)
{
    __shared__ float4 smem[1536];   // Qr[16][16] | Qi[16][16] | re[16][32] | im[16][32]
    const int t = threadIdx.x;
    const int bid = blockIdx.x;
    {
        const float4* gqr = (const float4*)Qr;
        const float4* gqi = (const float4*)Qi;
        const float4* gre = (const float4*)re;
        const float4* gim = (const float4*)im;
        for (int i = t; i < 1536; i += 256) {
            float4 v;
            if (i < 256)       v = gqr[(size_t)bid * 256 + i];
            else if (i < 512)  v = gqi[(size_t)bid * 256 + (i - 256)];
            else if (i < 1024) v = gre[(size_t)bid * 512 + (i - 512)];
            else               v = gim[(size_t)bid * 512 + (i - 1024)];
            smem[i] = v;
        }
    }
    __syncthreads();
    const int kt = t >> 4;       // k-quad 0..15
    const int c8 = t & 15;       // 8-col group 0..15
    float aU[4][8] = {}, aV[4][8] = {};
#pragma unroll 4
    for (int rr = 0; rr < ROWS; ++rr) {
        float4 q_r = smem[rr * 16 + kt];
        float4 q_i = smem[256 + rr * 16 + kt];
        float4 x_r0 = smem[512 + rr * 32 + c8 * 2];
        float4 x_r1 = smem[512 + rr * 32 + c8 * 2 + 1];
        float4 x_i0 = smem[1024 + rr * 32 + c8 * 2];
        float4 x_i1 = smem[1024 + rr * 32 + c8 * 2 + 1];
        float qr_[4] = {q_r.x, q_r.y, q_r.z, q_r.w};
        float qi_[4] = {q_i.x, q_i.y, q_i.z, q_i.w};
        float xr_[8] = {x_r0.x, x_r0.y, x_r0.z, x_r0.w, x_r1.x, x_r1.y, x_r1.z, x_r1.w};
        float xi_[8] = {x_i0.x, x_i0.y, x_i0.z, x_i0.w, x_i1.x, x_i1.y, x_i1.z, x_i1.w};
#pragma unroll
        for (int a = 0; a < 4; ++a)
#pragma unroll
            for (int b = 0; b < 8; ++b) {
                aU[a][b] = fmaf(qr_[a], xr_[b], aU[a][b]);
                aU[a][b] = fmaf(qi_[a], xi_[b], aU[a][b]);
                aV[a][b] = fmaf(qi_[a], xr_[b], aV[a][b]);
                aV[a][b] = fmaf(-qr_[a], xi_[b], aV[a][b]);
            }
    }
    float* base = part + (size_t)bid * 16384;
    const int k0 = kt * 4, c0 = c8 * 8;
#pragma unroll
    for (int a = 0; a < 4; ++a) {
        *(float4*)(base + (k0 + a) * CC + c0)            = make_float4(aU[a][0], aU[a][1], aU[a][2], aU[a][3]);
        *(float4*)(base + (k0 + a) * CC + c0 + 4)        = make_float4(aU[a][4], aU[a][5], aU[a][6], aU[a][7]);
        *(float4*)(base + 8192 + (k0 + a) * CC + c0)     = make_float4(aV[a][0], aV[a][1], aV[a][2], aV[a][3]);
        *(float4*)(base + 8192 + (k0 + a) * CC + c0 + 4) = make_float4(aV[a][4], aV[a][5], aV[a][6], aV[a][7]);
    }
}

// ---------------- kRB: reduce 625 partials -> row, then UVW = TT * (row @ W) ----------------
// 128 blocks = (m,k); 1024 threads = 32 q x 32 depth-groups (16 waves/block)
__global__ __launch_bounds__(1024) void kRB(const float* __restrict__ part,
                                            const float* __restrict__ Ritz,
                                            const int* __restrict__ ldp,
                                            const float* __restrict__ W,
                                            float* __restrict__ UVW)
{
    __shared__ float4 red4[1024];    // [d][q]
    __shared__ float  rowS[128];
    const int t = threadIdx.x;
    const int m = blockIdx.x >> 6, k = blockIdx.x & 63;
    const int q = t & 31, d = t >> 5;     // d: 0..31
    const float4* p0 = (const float4*)part + (size_t)m * 2048 + k * 32 + q;
    const float4 z = make_float4(0.f, 0.f, 0.f, 0.f);
    float4 s0 = z, s1 = z;
    int pp = d;
    for (; pp + 32 < NCH; pp += 64) {     // 2 independent chains
        s0 = f4add(s0, p0[(size_t)pp * PART_F4]);
        s1 = f4add(s1, p0[(size_t)(pp + 32) * PART_F4]);
    }
    if (pp < NCH) s0 = f4add(s0, p0[(size_t)pp * PART_F4]);
    red4[t] = f4add(s0, s1);
    __syncthreads();
    if (t < 32) {
        float4 tot = z;
#pragma unroll
        for (int dd = 0; dd < 32; ++dd) tot = f4add(tot, red4[dd * 32 + t]);
        ((float4*)rowS)[t] = tot;
    }
    __syncthreads();
    if (t < 128) {
        float acc = 0.f;
#pragma unroll 8
        for (int cp = 0; cp < 128; ++cp)
            acc = fmaf(rowS[cp], W[cp * 128 + t], acc);
        const int ld = *ldp;
        const float rz = Ritz[k];
        float tt = 1.f;
        for (int i = 0; i < ld; ++i) tt *= rz;
        UVW[m * 8192 + k * 128 + t] = tt * acc;
    }
}

// ---------------- kC: res = Q @ UVW + masked-ReLU, split-K cohorts ----------------
// 625 blocks x 256 threads: cohort kh in {0,1} handles k in [kh*32,(kh+1)*32).
// thread = 4 rows x 4 cols; LDS combine laid out [reg][thread] -> conflict-free.
__global__ __launch_bounds__(256) void kC(const float* __restrict__ re,
                                          const float* __restrict__ im,
                                          const float* __restrict__ Qr,
                                          const float* __restrict__ Qi,
                                          const float* __restrict__ UVW,
                                          float* __restrict__ out)
{
    __shared__ float4 xch[1024];        // 8 arrays[128] : R0..R3, I0..I3
    const int t = threadIdx.x;
    const int ct = t & 31;              // f4 col group
    const int rq = (t >> 5) & 3;        // 0..3
    const int kh = t >> 7;              // cohort 0/1
    const int r0 = blockIdx.x * 16 + rq * 4;
    const int idx = rq * 32 + ct;       // 0..127 within cohort
    const float4* U4 = (const float4*)UVW;     // [64][32]
    const float4* V4 = U4 + 2048;
    const float4* qr0 = (const float4*)(Qr + (size_t)r0 * KK);
    const float4* qi0 = (const float4*)(Qi + (size_t)r0 * KK);

    const float4 z = make_float4(0.f, 0.f, 0.f, 0.f);
    float4 R[4] = {z, z, z, z}, I[4] = {z, z, z, z};

    const int k4lo = kh * 8;
#pragma unroll
    for (int k4 = k4lo; k4 < k4lo + 8; ++k4) {
        float4 qr[4], qi[4];
#pragma unroll
        for (int j = 0; j < 4; ++j) {
            qr[j] = qr0[j * 16 + k4];
            qi[j] = qi0[j * 16 + k4];
        }
#pragma unroll
        for (int jj = 0; jj < 4; ++jj) {
            const int k = k4 * 4 + jj;
            float4 uw = U4[k * 32 + ct];
            float4 vw = V4[k * 32 + ct];
#pragma unroll
            for (int j = 0; j < 4; ++j) {
                float ar[4] = {qr[j].x, qr[j].y, qr[j].z, qr[j].w};
                float ai[4] = {qi[j].x, qi[j].y, qi[j].z, qi[j].w};
                R[j] = f4fma(ar[jj], uw, R[j]); R[j] = f4fma(ai[jj], vw, R[j]);
                I[j] = f4fma(ai[jj], uw, I[j]); I[j] = f4fma(-ar[jj], vw, I[j]);
            }
        }
    }
    if (kh == 1) {
#pragma unroll
        for (int j = 0; j < 4; ++j) {
            xch[j * 128 + idx]       = R[j];
            xch[(4 + j) * 128 + idx] = I[j];
        }
    }
    __syncthreads();
    if (kh == 0) {
#pragma unroll
        for (int j = 0; j < 4; ++j) {
            R[j] = f4add(R[j], xch[j * 128 + idx]);
            I[j] = f4add(I[j], xch[(4 + j) * 128 + idx]);
        }
        const int cc = ct * 4;
#pragma unroll
        for (int j = 0; j < 4; ++j) {
            const int row = r0 + j;
            float4 rin = *(const float4*)(re + (size_t)row * CC + cc);
            float4 iin = *(const float4*)(im + (size_t)row * CC + cc);
            float4 orr, oii;
            orr.x = rin.x + (R[j].x >= 0.f ? R[j].x : 0.f); oii.x = iin.x + (R[j].x >= 0.f ? I[j].x : 0.f);
            orr.y = rin.y + (R[j].y >= 0.f ? R[j].y : 0.f); oii.y = iin.y + (R[j].y >= 0.f ? I[j].y : 0.f);
            orr.z = rin.z + (R[j].z >= 0.f ? R[j].z : 0.f); oii.z = iin.z + (R[j].z >= 0.f ? I[j].z : 0.f);
            orr.w = rin.w + (R[j].w >= 0.f ? R[j].w : 0.f); oii.w = iin.w + (R[j].w >= 0.f ? I[j].w : 0.f);
            *(float4*)(out + (size_t)row * CC + cc)          = orr;
            *(float4*)(out + OUTOFF + (size_t)row * CC + cc) = oii;
        }
    }
}

extern "C" void kernel_launch(void* const* d_in, const int* in_sizes, int n_in,
                              void* d_out, int out_size, void* d_ws, size_t ws_size,
                              hipStream_t stream) {
    const float* re   = (const float*)d_in[0];
    const float* im   = (const float*)d_in[1];
    const float* Qr   = (const float*)d_in[2];
    const float* Qi   = (const float*)d_in[3];
    const float* Ritz = (const float*)d_in[4];
    const float* W    = (const float*)d_in[5];
    const int*   ldp  = (const int*)d_in[6];
    float* out = (float*)d_out;
    float* ws  = (float*)d_ws;

    float* part = ws;                      // 625 * 16384 floats (41 MB)
    float* UVW  = ws + UVW_OFF;            // 16384 floats

    kA <<<NCH, 256,  0, stream>>>(re, im, Qr, Qi, part);
    kRB<<<128, 1024, 0, stream>>>(part, Ritz, ldp, W, UVW);
    kC <<<NCH, 256,  0, stream>>>(re, im, Qr, Qi, UVW, out);
}

// Round 7
// 117.237 us; speedup vs baseline: 2.0552x; 1.0419x over previous
//
#include <hip/hip_runtime.h>

#define NN 10000
#define KK 64
#define CC 128
#define OUTOFF (NN * CC)
#define NA 256        // split-K blocks in kA
#define CHUNKS_A 625  // 625 * 16 == 10000

__device__ __forceinline__ float4 f4fma(float s, float4 v, float4 a) {
    a.x = fmaf(s, v.x, a.x); a.y = fmaf(s, v.y, a.y);
    a.z = fmaf(s, v.z, a.z); a.w = fmaf(s, v.w, a.w);
    return a;
}
__device__ __forceinline__ float4 f4add(float4 a, float4 b) {
    a.x += b.x; a.y += b.y; a.z += b.z; a.w += b.w; return a;
}

// ws layout (floats): [0 .. NA*16384)  partials [b][m][k][c]   (16.8 MB)
//                     [NA*16384 .. +16384)  UVW [m][k][c]      (64 KB)

// ---------------- kA: partial U,V = split-K of Q^H X (prefetch-pipelined, R0-proven) --------
__global__ __launch_bounds__(512) void kA(const float* __restrict__ re,
                                          const float* __restrict__ im,
                                          const float* __restrict__ Qr,
                                          const float* __restrict__ Qi,
                                          float* __restrict__ part)
{
    __shared__ float4 smem[1536];   // 24 KB: Qr 256 | Qi 256 | re 512 | im 512
    const int t = threadIdx.x;
    const int bid = blockIdx.x;
    const int kt = t & 15;        // k0 = 4*kt
    const int ctA = t >> 4;       // c0 = 4*ctA (0..31)
    const int row_q = (t & 255) >> 4, q_q = t & 15;
    const int row_x = t >> 5,          q_x = t & 31;
    const float4* gq  = (const float4*)((t < 256) ? Qr : Qi);   // wave-uniform select
    const float4* gre = (const float4*)re;
    const float4* gim = (const float4*)im;

    float aU[4][4] = {}, aV[4][4] = {};

    int cb = bid;
    float4 r0 = gq [(size_t)(cb * 16 + row_q) * 16 + q_q];
    float4 r1 = gre[(size_t)(cb * 16 + row_x) * 32 + q_x];
    float4 r2 = gim[(size_t)(cb * 16 + row_x) * 32 + q_x];

    while (true) {
        smem[t] = r0; smem[512 + t] = r1; smem[1024 + t] = r2;
        __syncthreads();
        const int nx = cb + NA;
        if (nx < CHUNKS_A) {   // prefetch next chunk into registers during compute
            const int m0 = nx * 16;
            r0 = gq [(size_t)(m0 + row_q) * 16 + q_q];
            r1 = gre[(size_t)(m0 + row_x) * 32 + q_x];
            r2 = gim[(size_t)(m0 + row_x) * 32 + q_x];
        }
#pragma unroll 4
        for (int rr = 0; rr < 16; ++rr) {
            float4 q_r = smem[rr * 16 + kt];
            float4 q_i = smem[256 + rr * 16 + kt];
            float4 x_r = smem[512 + rr * 32 + ctA];
            float4 x_i = smem[1024 + rr * 32 + ctA];
            float qr_[4] = {q_r.x, q_r.y, q_r.z, q_r.w};
            float qi_[4] = {q_i.x, q_i.y, q_i.z, q_i.w};
            float xr_[4] = {x_r.x, x_r.y, x_r.z, x_r.w};
            float xi_[4] = {x_i.x, x_i.y, x_i.z, x_i.w};
#pragma unroll
            for (int a = 0; a < 4; ++a)
#pragma unroll
                for (int b = 0; b < 4; ++b) {
                    aU[a][b] = fmaf(qr_[a], xr_[b], aU[a][b]);
                    aU[a][b] = fmaf(qi_[a], xi_[b], aU[a][b]);
                    aV[a][b] = fmaf(qi_[a], xr_[b], aV[a][b]);
                    aV[a][b] = fmaf(-qr_[a], xi_[b], aV[a][b]);
                }
        }
        __syncthreads();
        if (nx >= CHUNKS_A) break;
        cb = nx;
    }
    float* base = part + (size_t)bid * 16384;
    const int k0 = kt * 4, c0 = ctA * 4;
#pragma unroll
    for (int a = 0; a < 4; ++a) {
        *(float4*)(base + (k0 + a) * CC + c0)        = make_float4(aU[a][0], aU[a][1], aU[a][2], aU[a][3]);
        *(float4*)(base + 8192 + (k0 + a) * CC + c0) = make_float4(aV[a][0], aV[a][1], aV[a][2], aV[a][3]);
    }
}

// ---------------- kRB: reduce 256 partials -> row, then UVW = TT * row @ W (R0-proven) ------
__global__ __launch_bounds__(256) void kRB(const float* __restrict__ part,
                                           const float* __restrict__ Ritz,
                                           const int* __restrict__ ldp,
                                           const float* __restrict__ W,
                                           float* __restrict__ UVW)
{
    __shared__ float4 red4[256];
    __shared__ float rowS[128];
    const int t = threadIdx.x;
    const int m = blockIdx.x >> 6, k = blockIdx.x & 63;
    const int q = t & 31, sl = t >> 5;   // q: float4 col group, sl: slice lane (0..7)

    const float4* p = (const float4*)part + (size_t)sl * 4096 + m * 2048 + k * 32 + q;
    float4 z = make_float4(0.f, 0.f, 0.f, 0.f);
    float4 s0 = z, s1 = z, s2 = z, s3 = z;
#pragma unroll 2
    for (int jj = 0; jj < 8; ++jj) {
        s0 = f4add(s0, p[0]);
        s1 = f4add(s1, p[(size_t)8  * 4096]);
        s2 = f4add(s2, p[(size_t)16 * 4096]);
        s3 = f4add(s3, p[(size_t)24 * 4096]);
        p += (size_t)32 * 4096;
    }
    red4[t] = f4add(f4add(s0, s1), f4add(s2, s3));
    __syncthreads();
    if (t < 32) {
        float4 tot = z;
#pragma unroll
        for (int g = 0; g < 8; ++g) tot = f4add(tot, red4[g * 32 + t]);
        ((float4*)rowS)[t] = tot;
    }
    __syncthreads();
    if (t < 128) {
        float acc = 0.f;
#pragma unroll 8
        for (int cp = 0; cp < 128; ++cp)
            acc = fmaf(rowS[cp], W[cp * 128 + t], acc);
        const int ld = *ldp;
        const float rz = Ritz[k];
        float tt = 1.f;
        for (int i = 0; i < ld; ++i) tt *= rz;
        UVW[m * 8192 + k * 128 + t] = tt * acc;
    }
}

// ---------------- kC: res = Q @ UVW + masked-ReLU, rr=2 + k-cohort split ----------------
// 625 blocks x 512 threads: kh = t>>8 handles k4 in [kh*8, kh*8+8).
// thread = 2 rows (na, na+8) x 4 cols; 5000 waves = 4.9 waves/SIMD.
// UVW read direct (L1-hot, wave-broadcast 512B lines); 16 KB LDS combine -> no occupancy cap.
__global__ __launch_bounds__(512) void kC(const float* __restrict__ re,
                                          const float* __restrict__ im,
                                          const float* __restrict__ Qr,
                                          const float* __restrict__ Qi,
                                          const float* __restrict__ UVW,
                                          float* __restrict__ out)
{
    __shared__ float4 xch[4][256];      // 16 KB: Ra, Ia, Rb, Ib from cohort 1
    const int t = threadIdx.x;
    const int ct = t & 31;              // f4 col group
    const int r  = (t >> 5) & 7;        // 0..7
    const int kh = t >> 8;              // cohort 0/1
    const int na = blockIdx.x * 16 + r; // rows na and na+8
    const int nb = na + 8;
    const int idx = r * 32 + ct;        // 0..255

    const float4* U4 = (const float4*)UVW;   // [64][32] f4
    const float4* V4 = U4 + 2048;
    const float4* qra = (const float4*)(Qr + (size_t)na * KK);
    const float4* qia = (const float4*)(Qi + (size_t)na * KK);
    const float4* qrb = (const float4*)(Qr + (size_t)nb * KK);
    const float4* qib = (const float4*)(Qi + (size_t)nb * KK);

    const float4 z = make_float4(0.f, 0.f, 0.f, 0.f);
    float4 Ra = z, Ia = z, Rb = z, Ib = z;

    const int k4base = kh * 8;
#pragma unroll
    for (int k4i = 0; k4i < 8; ++k4i) {
        const int k4 = k4base + k4i;
        float4 QRa = qra[k4], QIa = qia[k4];
        float4 QRb = qrb[k4], QIb = qib[k4];
        float ar[4] = {QRa.x, QRa.y, QRa.z, QRa.w};
        float ai[4] = {QIa.x, QIa.y, QIa.z, QIa.w};
        float br[4] = {QRb.x, QRb.y, QRb.z, QRb.w};
        float bi[4] = {QIb.x, QIb.y, QIb.z, QIb.w};
#pragma unroll
        for (int jj = 0; jj < 4; ++jj) {
            const int k = k4 * 4 + jj;
            float4 uw = U4[k * 32 + ct];
            float4 vw = V4[k * 32 + ct];
            Ra = f4fma(ar[jj], uw, Ra); Ra = f4fma(ai[jj], vw, Ra);
            Ia = f4fma(ai[jj], uw, Ia); Ia = f4fma(-ar[jj], vw, Ia);
            Rb = f4fma(br[jj], uw, Rb); Rb = f4fma(bi[jj], vw, Rb);
            Ib = f4fma(bi[jj], uw, Ib); Ib = f4fma(-br[jj], vw, Ib);
        }
    }
    if (kh == 1) {
        xch[0][idx] = Ra; xch[1][idx] = Ia;
        xch[2][idx] = Rb; xch[3][idx] = Ib;
    }
    __syncthreads();
    if (kh == 0) {
        Ra = f4add(Ra, xch[0][idx]); Ia = f4add(Ia, xch[1][idx]);
        Rb = f4add(Rb, xch[2][idx]); Ib = f4add(Ib, xch[3][idx]);
        const int cc = ct * 4;
        {
            float4 rin = *(const float4*)(re + (size_t)na * CC + cc);
            float4 iin = *(const float4*)(im + (size_t)na * CC + cc);
            float4 orr, oii;
            orr.x = rin.x + (Ra.x >= 0.f ? Ra.x : 0.f); oii.x = iin.x + (Ra.x >= 0.f ? Ia.x : 0.f);
            orr.y = rin.y + (Ra.y >= 0.f ? Ra.y : 0.f); oii.y = iin.y + (Ra.y >= 0.f ? Ia.y : 0.f);
            orr.z = rin.z + (Ra.z >= 0.f ? Ra.z : 0.f); oii.z = iin.z + (Ra.z >= 0.f ? Ia.z : 0.f);
            orr.w = rin.w + (Ra.w >= 0.f ? Ra.w : 0.f); oii.w = iin.w + (Ra.w >= 0.f ? Ia.w : 0.f);
            *(float4*)(out + (size_t)na * CC + cc)          = orr;
            *(float4*)(out + OUTOFF + (size_t)na * CC + cc) = oii;
        }
        {
            float4 rin = *(const float4*)(re + (size_t)nb * CC + cc);
            float4 iin = *(const float4*)(im + (size_t)nb * CC + cc);
            float4 orr, oii;
            orr.x = rin.x + (Rb.x >= 0.f ? Rb.x : 0.f); oii.x = iin.x + (Rb.x >= 0.f ? Ib.x : 0.f);
            orr.y = rin.y + (Rb.y >= 0.f ? Rb.y : 0.f); oii.y = iin.y + (Rb.y >= 0.f ? Ib.y : 0.f);
            orr.z = rin.z + (Rb.z >= 0.f ? Rb.z : 0.f); oii.z = iin.z + (Rb.z >= 0.f ? Ib.z : 0.f);
            orr.w = rin.w + (Rb.w >= 0.f ? Rb.w : 0.f); oii.w = iin.w + (Rb.w >= 0.f ? Ib.w : 0.f);
            *(float4*)(out + (size_t)nb * CC + cc)          = orr;
            *(float4*)(out + OUTOFF + (size_t)nb * CC + cc) = oii;
        }
    }
}

extern "C" void kernel_launch(void* const* d_in, const int* in_sizes, int n_in,
                              void* d_out, int out_size, void* d_ws, size_t ws_size,
                              hipStream_t stream) {
    const float* re   = (const float*)d_in[0];
    const float* im   = (const float*)d_in[1];
    const float* Qr   = (const float*)d_in[2];
    const float* Qi   = (const float*)d_in[3];
    const float* Ritz = (const float*)d_in[4];
    const float* W    = (const float*)d_in[5];
    const int*   ldp  = (const int*)d_in[6];
    float* out = (float*)d_out;
    float* ws  = (float*)d_ws;

    float* part = ws;                          // NA * 16384 floats (16.8 MB)
    float* UVW  = ws + (size_t)NA * 16384;     // 16384 floats

    kA <<<NA,  512, 0, stream>>>(re, im, Qr, Qi, part);
    kRB<<<128, 256, 0, stream>>>(part, Ritz, ldp, W, UVW);
    kC <<<625, 512, 0, stream>>>(re, im, Qr, Qi, UVW, out);
}